// Round 10
// baseline (581.749 us; speedup 1.0000x reference)
//
#include <hip/hip_runtime.h>
#include <hip/hip_bf16.h>
#include <cstdio>

#define N_NODES 100000
#define E_EDGES 3200000
#define N_GRAPH 512
#define HDIM 64
#define BN_EPS 1e-5f
#define NBUCKET ((N_NODES + 255) / 256)   // 391 buckets of 256 nodes
#define NCHUNK 256                        // edge chunks (radix partition)
#define CHUNK ((E_EDGES + NCHUNK - 1) / NCHUNK) // 12500 edges/chunk
#define SORT_CAP 12288                    // per-bucket LDS entries (max region ~9.6k)
#define NPW 8                             // nodes per wave in agg kernels (2 concurrent)
#define WT_STRIDE 76                      // transposed-W LDS stride: 16B-aligned, start banks 12f%32 -> 2-way (free)
#define BSLACK 1028                       // per-bucket reserved pad slack (4-aligned)

typedef _Float16 f16;
typedef _Float16 half8 __attribute__((ext_vector_type(8)));

// ======== counter-free radix partition of edges by dst>>8 ========

__global__ __launch_bounds__(256) void hist_k(const int* __restrict__ dst,
                                              int* __restrict__ histT) {
    __shared__ int h[NBUCKET];
    int c = blockIdx.x, t = threadIdx.x;
    for (int i = t; i < NBUCKET; i += 256) h[i] = 0;
    __syncthreads();
    int e0 = c * CHUNK;
    int e1 = min(e0 + CHUNK, E_EDGES);
    for (int e = e0 + t; e < e1; e += 256)
        atomicAdd(&h[__builtin_nontemporal_load(dst + e) >> 8], 1);
    __syncthreads();
    for (int i = t; i < NBUCKET; i += 256) histT[i * NCHUNK + c] = h[i];
}

// bucket totals + exclusive scan; ALSO precomputes layer-1 affine m1c1[f]
__global__ void scanA_k(const int* __restrict__ histT, int* __restrict__ bucket_base,
                        const float* __restrict__ w1, const float* __restrict__ b1,
                        const float* __restrict__ bg1, const float* __restrict__ bb1,
                        const float* __restrict__ brm1, const float* __restrict__ brv1,
                        float2* __restrict__ m1c1) {
    __shared__ int sh[512];
    int t = threadIdx.x;
    if (t < HDIM) {
        float sc1 = bg1[t] * rsqrtf(brv1[t] + BN_EPS);
        m1c1[t] = make_float2(sc1 * w1[t], (b1[t] - brm1[t]) * sc1 + bb1[t]);
    }
    int sum = 0;
    if (t < NBUCKET) {
        const int* row = histT + t * NCHUNK;
        for (int c = 0; c < NCHUNK; c++) sum += row[c];
    }
    sh[t] = sum;
    __syncthreads();
    for (int off = 1; off < 512; off <<= 1) {
        int add = (t >= off) ? sh[t - off] : 0;
        __syncthreads();
        sh[t] += add;
        __syncthreads();
    }
    if (t < NBUCKET) bucket_base[t] = sh[t] - sum;
    if (t == 0) bucket_base[NBUCKET] = E_EDGES;
}

__global__ __launch_bounds__(NCHUNK) void scanB_k(const int* __restrict__ histT,
                                                  const int* __restrict__ bucket_base,
                                                  int* __restrict__ scannedT) {
    __shared__ int sh[NCHUNK];
    int b = blockIdx.x, t = threadIdx.x;
    int v = histT[b * NCHUNK + t];
    sh[t] = v;
    __syncthreads();
    for (int off = 1; off < NCHUNK; off <<= 1) {
        int add = (t >= off) ? sh[t - off] : 0;
        __syncthreads();
        sh[t] += add;
        __syncthreads();
    }
    scannedT[b * NCHUNK + t] = bucket_base[b] + sh[t] - v;
}

__global__ __launch_bounds__(256) void scatter_k(const int* __restrict__ src,
                                                 const int* __restrict__ dst,
                                                 const int* __restrict__ scannedT,
                                                 int* __restrict__ staging) {
    __shared__ int lcnt[NBUCKET];
    int c = blockIdx.x, t = threadIdx.x;
    for (int i = t; i < NBUCKET; i += 256) lcnt[i] = scannedT[i * NCHUNK + c];
    __syncthreads();
    int e0 = c * CHUNK;
    int e1 = min(e0 + CHUNK, E_EDGES);
    for (int e = e0 + t; e < e1; e += 256) {
        int v = __builtin_nontemporal_load(dst + e);
        int u = __builtin_nontemporal_load(src + e);
        int pos = atomicAdd(&lcnt[v >> 8], 1);       // LDS atomic
        staging[pos] = u | ((v & 255) << 17);        // 4B, ~128B runs per bucket
    }
}

// ======== per-bucket: node degrees -> ptr_raw/dinv/xtil ========

__global__ __launch_bounds__(256) void nodeptr_k(const int* __restrict__ staging,
                                                 const int* __restrict__ bucket_base,
                                                 const float* __restrict__ x,
                                                 int* __restrict__ ptr_raw,
                                                 float* __restrict__ dinv,
                                                 float* __restrict__ xtil) {
    __shared__ int hn[256];
    __shared__ int sc[256];
    int t = threadIdx.x, b = blockIdx.x;
    int v0 = b << 8;
    int p0 = bucket_base[b], p1 = bucket_base[b + 1];
    hn[t] = 0;
    __syncthreads();
    int cnt = p1 - p0;
    for (int i = t; i < cnt; i += 256)
        atomicAdd(&hn[staging[p0 + i] >> 17], 1);
    __syncthreads();
    int my = hn[t];
    sc[t] = my;
    __syncthreads();
    for (int off = 1; off < 256; off <<= 1) {
        int add = (t >= off) ? sc[t - off] : 0;
        __syncthreads();
        sc[t] += add;
        __syncthreads();
    }
    int v = v0 + t;
    if (v < N_NODES) {
        ptr_raw[v] = p0 + sc[t] - my;
        float dv = rsqrtf((float)(my + 1));
        dinv[v] = dv;
        xtil[v] = dv * x[v];
    }
    if (b == NBUCKET - 1 && t == 0) ptr_raw[N_NODES] = E_EDGES;
}

// ======== per-bucket: padded CSR (reserved bases, sentinel fill) + fused layer-1 sum ====
// Bucket b's padded region: [pb0, pbend) where pb0=(bbase[b]&~3)+1028*b. The whole
// region is sentinel-initialized; node pads AND inter-node/bucket gaps read as node N.

__global__ __launch_bounds__(256) void csr_l1_k(const int* __restrict__ staging,
                                                const int* __restrict__ ptr_raw,
                                                const float* __restrict__ dinv,
                                                const float* __restrict__ xtil,
                                                const float* __restrict__ x,
                                                int* __restrict__ csr,
                                                int* __restrict__ ptr_pad,
                                                float2* __restrict__ pairs) {
    __shared__ int lbase[257];
    __shared__ int plp[257];
    __shared__ int ss[256];
    __shared__ int lcnt[256];
    __shared__ int lds_u[SORT_CAP];
    int t = threadIdx.x, b = blockIdx.x;
    int v0 = b << 8;
    for (int i = t; i < 257; i += 256) {
        int vv = v0 + i;
        lbase[i] = ptr_raw[(vv < N_NODES) ? vv : N_NODES];
    }
    lcnt[t] = 0;
    __syncthreads();
    int p0 = lbase[0];
    int pb0 = (p0 & ~3) + BSLACK * b;
    int pbend = (lbase[256] & ~3) + BSLACK * (b + 1);
    int deg = lbase[t + 1] - lbase[t];
    int pd = (deg + 3) & ~3;
    ss[t] = pd;
    __syncthreads();
    for (int off = 1; off < 256; off <<= 1) {
        int add = (t >= off) ? ss[t - off] : 0;
        __syncthreads();
        ss[t] += add;
        __syncthreads();
    }
    plp[t] = ss[t] - pd;                  // exclusive padded prefix
    if (t == 255) plp[256] = ss[255];
    __syncthreads();
    int cnt = lbase[256] - p0;
    int R4 = (pbend - pb0) >> 2;          // whole reserved region, 4-aligned
    int4 sent = {N_NODES, N_NODES, N_NODES, N_NODES};
    for (int i = t; i < R4; i += 256) {
        if (i < (SORT_CAP >> 2)) ((int4*)lds_u)[i] = sent;
        else ((int4*)(csr + pb0))[i] = sent;      // overflow region (rare)
    }
    __syncthreads();
    for (int i = t; i < cnt; i += 256) {
        int packed = staging[p0 + i];      // L2-hot re-read
        int u = packed & 0x1FFFF;
        int vl = packed >> 17;
        int r = atomicAdd(&lcnt[vl], 1);   // LDS atomic
        int pos = plp[vl] + r;
        if (pos < SORT_CAP) lds_u[pos] = u;
        else csr[pb0 + pos] = u;
    }
    __syncthreads();
    int lim4 = min(R4, SORT_CAP >> 2);
    for (int i = t; i < lim4; i += 256)
        ((int4*)(csr + pb0))[i] = ((int4*)lds_u)[i];   // coalesced 16B copy
    __syncthreads();
    int v = v0 + t;
    if (v < N_NODES) {
        int j0 = plp[t];
        ptr_pad[v] = pb0 + j0;
        float s = 0.f;
        for (int j = j0; j < j0 + deg; j++) {
            int u = (j < SORT_CAP) ? lds_u[j] : csr[pb0 + j];
            s += xtil[u];                  // 400KB L2-resident table
        }
        float dv = dinv[v];
        pairs[v] = make_float2(dv * s + dv * dv * x[v], dv);
    }
    if (b == NBUCKET - 1 && t == 0) ptr_pad[N_NODES] = pbend;
    if (b == 0 && t == 0) pairs[N_NODES] = make_float2(0.f, 0.f);  // sentinel
}

// ======== Layer 2: half-wave per node (2 concurrent nodes/wave) ========
// Half h=lane>>5 owns node v0+2r+h: 4 edge-quad slots (o2) x 8 feature lanes (s).
// Per edge: reconstruct x1til[u,f]=d_u*relu(m1 f s_u + c1 f) from 8B pairs gather.
// Epilogue per node uses the full wave (compile-time readlane into the owning half).

__global__ __launch_bounds__(256, 8) void agg_l2_k(
    const float2* __restrict__ pairs, const float2* __restrict__ m1c1,
    f16* __restrict__ xout,
    const int* __restrict__ ptr_pad, const int* __restrict__ csr,
    const float* __restrict__ W2, const float* __restrict__ bias2,
    const float* __restrict__ bg2, const float* __restrict__ bb2,
    const float* __restrict__ brm2, const float* __restrict__ brv2) {
    __shared__ float wsh_t[HDIM * WT_STRIDE];
    __shared__ float sM[HDIM], sC[HDIM];
    int tid = threadIdx.x;
    for (int i = tid; i < HDIM * HDIM; i += 256)
        wsh_t[(i & 63) * WT_STRIDE + (i >> 6)] = W2[i];    // transpose: [f][k]
    if (tid < HDIM) {
        float sc = bg2[tid] * rsqrtf(brv2[tid] + BN_EPS);
        sM[tid] = sc;
        sC[tid] = (bias2[tid] - brm2[tid]) * sc + bb2[tid];
    }
    __syncthreads();

    int lane = tid & 63;
    int h = lane >> 5;
    int o2 = (lane >> 3) & 3;
    int s = lane & 7;
    int f = lane;
    // sentinel row of xout (read by layer 3)
    if (blockIdx.x == 0 && tid < HDIM) xout[(size_t)N_NODES * HDIM + tid] = (f16)0.f;

    float m1[8], c1[8];
#pragma unroll
    for (int i = 0; i < 8; i++) {
        float2 mc = m1c1[s * 8 + i];
        m1[i] = mc.x; c1[i] = mc.y;
    }
    const float4* wt4 = (const float4*)&wsh_t[f * WT_STRIDE];

    int v0 = (blockIdx.x * 4 + (tid >> 6)) * NPW;
    for (int r = 0; r < NPW / 2; r++) {
        int v = v0 + 2 * r + h;                     // per-half node
        bool valid = v < N_NODES;
        int e0 = valid ? ptr_pad[v] : 0;
        int pe1 = valid ? ptr_pad[v + 1] : 0;
        float2 pv = valid ? pairs[v] : make_float2(0.f, 0.f);
        float acc[8];
        {
            float cf = (o2 == 0) ? pv.y : 0.f;      // self-loop, once per node
#pragma unroll
            for (int i = 0; i < 8; i++)
                acc[i] = cf * fmaxf(m1[i] * pv.x + c1[i], 0.f);
        }
        for (int e = e0; e < pe1; e += 16) {
            int bb = e + o2 * 4;
            if (bb < pe1) {
                int4 u4 = *(const int4*)(csr + bb); // 16B: 4 edges
                int uu[4] = {u4.x, u4.y, u4.z, u4.w};
#pragma unroll
                for (int c = 0; c < 4; c++) {
                    float2 p = pairs[uu[c]];        // 8B gather, L2-resident; sentinel->0
#pragma unroll
                    for (int i = 0; i < 8; i++)
                        acc[i] += p.y * fmaxf(m1[i] * p.x + c1[i], 0.f);
                }
            }
        }
#pragma unroll
        for (int i = 0; i < 8; i++) {               // reduce within half
            acc[i] += __shfl_xor(acc[i], 8);
            acc[i] += __shfl_xor(acc[i], 16);
        }
        // epilogue: full wave per node; feature k lives at lane hh*32+(k>>3), reg k&7
#pragma unroll
        for (int hh = 0; hh < 2; hh++) {
            int vv = v0 + 2 * r + hh;
            if (vv >= N_NODES) break;
            float ov = 0.f;
#pragma unroll
            for (int k4 = 0; k4 < 16; k4++) {
                float4 w4 = wt4[k4];                // conflict-free b128
                float wc[4] = {w4.x, w4.y, w4.z, w4.w};
#pragma unroll
                for (int j = 0; j < 4; j++) {
                    int k = k4 * 4 + j;
                    ov += __shfl(acc[k & 7], hh * 32 + (k >> 3)) * wc[j];
                }
            }
            float dvv = __shfl(pv.y, hh * 32);
            float val = fmaxf(dvv * ov * sM[f] + sC[f], 0.f);
            xout[(size_t)vv * HDIM + f] = (f16)(dvv * val);   // pre-scaled for layer 3
        }
    }
}

// ======== Layer 3: half-wave fp16 row gather + fused @W3 + BN + ReLU ========

__global__ __launch_bounds__(256, 8) void agg_gemm_k(
    const f16* __restrict__ xin, f16* __restrict__ xout,
    const int* __restrict__ ptr_pad, const int* __restrict__ csr,
    const float2* __restrict__ pairs,
    const float* __restrict__ W, const float* __restrict__ bias,
    const float* __restrict__ bg, const float* __restrict__ bb,
    const float* __restrict__ brm, const float* __restrict__ brv) {
    __shared__ float wsh_t[HDIM * WT_STRIDE];
    __shared__ float sM[HDIM], sC[HDIM];
    int tid = threadIdx.x;
    for (int i = tid; i < HDIM * HDIM; i += 256)
        wsh_t[(i & 63) * WT_STRIDE + (i >> 6)] = W[i];
    if (tid < HDIM) {
        float sc = bg[tid] * rsqrtf(brv[tid] + BN_EPS);
        sM[tid] = sc;
        sC[tid] = (bias[tid] - brm[tid]) * sc + bb[tid];
    }
    __syncthreads();

    int lane = tid & 63;
    int h = lane >> 5;
    int o2 = (lane >> 3) & 3;
    int s = lane & 7;
    int f = lane;
    const half8* __restrict__ xin8 = (const half8*)xin;
    const float4* wt4 = (const float4*)&wsh_t[f * WT_STRIDE];

    int v0 = (blockIdx.x * 4 + (tid >> 6)) * NPW;
    for (int r = 0; r < NPW / 2; r++) {
        int v = v0 + 2 * r + h;
        bool valid = v < N_NODES;
        int e0 = valid ? ptr_pad[v] : 0;
        int pe1 = valid ? ptr_pad[v + 1] : 0;
        float dvh = valid ? pairs[v].y : 0.f;
        float acc[8];
        {
            half8 rsl = xin8[(size_t)(valid ? v : N_NODES) * 8 + s];  // self-loop row
            float cf = (o2 == 0) ? 1.f : 0.f;
#pragma unroll
            for (int i = 0; i < 8; i++) acc[i] = cf * (float)rsl[i];
        }
        for (int e = e0; e < pe1; e += 16) {
            int bb = e + o2 * 4;
            if (bb < pe1) {
                int4 u4 = *(const int4*)(csr + bb);
                int uu[4] = {u4.x, u4.y, u4.z, u4.w};
#pragma unroll
                for (int c = 0; c < 4; c++) {
                    half8 rr = xin8[(size_t)uu[c] * 8 + s]; // 16B/lane; sentinel row = 0
#pragma unroll
                    for (int i = 0; i < 8; i++) acc[i] += (float)rr[i];
                }
            }
        }
#pragma unroll
        for (int i = 0; i < 8; i++) {
            acc[i] += __shfl_xor(acc[i], 8);
            acc[i] += __shfl_xor(acc[i], 16);
        }
#pragma unroll
        for (int hh = 0; hh < 2; hh++) {
            int vv = v0 + 2 * r + hh;
            if (vv >= N_NODES) break;
            float ov = 0.f;
#pragma unroll
            for (int k4 = 0; k4 < 16; k4++) {
                float4 w4 = wt4[k4];
                float wc[4] = {w4.x, w4.y, w4.z, w4.w};
#pragma unroll
                for (int j = 0; j < 4; j++) {
                    int k = k4 * 4 + j;
                    ov += __shfl(acc[k & 7], hh * 32 + (k >> 3)) * wc[j];
                }
            }
            float dvv = __shfl(dvh, hh * 32);
            float val = fmaxf(dvv * ov * sM[f] + sC[f], 0.f);
            xout[(size_t)vv * HDIM + f] = (f16)val;
        }
    }
}

// ======== Pool (mean/max per graph) + MLP head ========

__device__ inline int lower_bound_i(const int* __restrict__ a, int n, int val) {
    int lo = 0, hi = n;
    while (lo < hi) {
        int mid = (lo + hi) >> 1;
        if (a[mid] < val) lo = mid + 1; else hi = mid;
    }
    return lo;
}

__global__ void pool_mlp_k(const f16* __restrict__ x, const int* __restrict__ batch,
                           const float* __restrict__ wl1, const float* __restrict__ bl1,
                           const float* __restrict__ wl2, const float* __restrict__ bl2,
                           const float* __restrict__ bg, const float* __restrict__ bb,
                           const float* __restrict__ brm, const float* __restrict__ brv,
                           float* __restrict__ out) {
    int g = blockIdx.x;
    int tid = threadIdx.x;
    int w = tid >> 6;
    int f = tid & 63;
    int start = lower_bound_i(batch, N_NODES, g);
    int end = lower_bound_i(batch, N_NODES, g + 1);
    float sum = 0.f;
    float mx = -3.402823466e38f;
#pragma unroll 2
    for (int v = start + w; v < end; v += 4) {
        float val = (float)x[(size_t)v * HDIM + f];
        sum += val;
        mx = fmaxf(mx, val);
    }
    __shared__ float ssum[4][HDIM], smax[4][HDIM];
    __shared__ float zs[2 * HDIM];
    ssum[w][f] = sum;
    smax[w][f] = mx;
    __syncthreads();
    if (tid < 64) {
        float sm = ssum[0][f] + ssum[1][f] + ssum[2][f] + ssum[3][f];
        float m = fmaxf(fmaxf(smax[0][f], smax[1][f]), fmaxf(smax[2][f], smax[3][f]));
        float cnt = (float)(end - start);
        zs[f] = sm / fmaxf(cnt, 1.f);
        zs[HDIM + f] = m;
    }
    __syncthreads();
    if (tid >= 64) return;

    float o = bl1[f];
#pragma unroll 8
    for (int k = 0; k < 2 * HDIM; k++) {
        o += zs[k] * wl1[k * HDIM + f];
    }
    float sc = bg[f] * rsqrtf(brv[f] + BN_EPS);
    o = fmaxf((o - brm[f]) * sc + bb[f], 0.f);

    float p0 = o * wl2[f * 2 + 0];
    float p1 = o * wl2[f * 2 + 1];
    for (int off = 32; off > 0; off >>= 1) {
        p0 += __shfl_down(p0, off);
        p1 += __shfl_down(p1, off);
    }
    if (f == 0) {
        out[g * 2 + 0] = p0 + bl2[0];
        out[g * 2 + 1] = p1 + bl2[1];
    }
}

// ======== launch ========

extern "C" void kernel_launch(void* const* d_in, const int* in_sizes, int n_in,
                              void* d_out, int out_size, void* d_ws, size_t ws_size,
                              hipStream_t stream) {
    const float* x    = (const float*)d_in[0];
    const int* src    = (const int*)d_in[1];
    const int* dst    = (const int*)d_in[2];
    const int* batch  = (const int*)d_in[3];
    const float* w1   = (const float*)d_in[4];
    const float* b1   = (const float*)d_in[5];
    const float* w2   = (const float*)d_in[6];
    const float* b2   = (const float*)d_in[7];
    const float* w3   = (const float*)d_in[8];
    const float* b3   = (const float*)d_in[9];
    const float* wl1  = (const float*)d_in[10];
    const float* bl1  = (const float*)d_in[11];
    const float* wl2  = (const float*)d_in[12];
    const float* bl2  = (const float*)d_in[13];
    const float* bn1g = (const float*)d_in[14];
    const float* bn1b = (const float*)d_in[15];
    const float* bn1rm = (const float*)d_in[16];
    const float* bn1rv = (const float*)d_in[17];
    const float* bn2g = (const float*)d_in[18];
    const float* bn2b = (const float*)d_in[19];
    const float* bn2rm = (const float*)d_in[20];
    const float* bn2rv = (const float*)d_in[21];
    const float* bn3g = (const float*)d_in[22];
    const float* bn3b = (const float*)d_in[23];
    const float* bn3rm = (const float*)d_in[24];
    const float* bn3rv = (const float*)d_in[25];
    const float* bnlg = (const float*)d_in[26];
    const float* bnlb = (const float*)d_in[27];
    const float* bnlrm = (const float*)d_in[28];
    const float* bnlrv = (const float*)d_in[29];
    float* out = (float*)d_out;

    char* ws = (char*)d_ws;
    size_t off = 0;
    auto alloc = [&](size_t bytes) -> char* {
        off = (off + 255) & ~(size_t)255;
        char* p = ws + off;
        off += bytes;
        return p;
    };
    int*    histT    = (int*)alloc((size_t)NBUCKET * NCHUNK * 4);
    int*    scannedT = (int*)alloc((size_t)NBUCKET * NCHUNK * 4);
    int*    bbase    = (int*)alloc((NBUCKET + 1) * 4);
    int*    staging  = (int*)alloc((size_t)E_EDGES * 4);
    int*    csr      = (int*)alloc(((size_t)E_EDGES + (size_t)BSLACK * NBUCKET + 64) * 4);
    int*    ptr_raw  = (int*)alloc(((size_t)N_NODES + 1) * 4);
    int*    ptr_pad  = (int*)alloc(((size_t)N_NODES + 1) * 4);
    float*  dinv     = (float*)alloc((size_t)N_NODES * 4);
    float*  xtil     = (float*)alloc((size_t)N_NODES * 4);
    float2* pairs    = (float2*)alloc(((size_t)N_NODES + 1) * 8);
    float2* m1c1     = (float2*)alloc((size_t)HDIM * 8);
    f16*    x2       = (f16*)alloc(((size_t)N_NODES + 1) * HDIM * 2);
    f16*    x3       = (f16*)alloc((size_t)N_NODES * HDIM * 2);
    if (off > ws_size) {
        fprintf(stderr, "kernel_launch: ws too small (%zu > %zu)\n", off, ws_size);
    }

    const int NB_AGG = (N_NODES + 4 * NPW - 1) / (4 * NPW);  // 3125

    hist_k<<<NCHUNK, 256, 0, stream>>>(dst, histT);
    scanA_k<<<1, 512, 0, stream>>>(histT, bbase, w1, b1, bn1g, bn1b, bn1rm, bn1rv, m1c1);
    scanB_k<<<NBUCKET, NCHUNK, 0, stream>>>(histT, bbase, scannedT);
    scatter_k<<<NCHUNK, 256, 0, stream>>>(src, dst, scannedT, staging);
    nodeptr_k<<<NBUCKET, 256, 0, stream>>>(staging, bbase, x, ptr_raw, dinv, xtil);
    csr_l1_k<<<NBUCKET, 256, 0, stream>>>(staging, ptr_raw, dinv, xtil, x,
                                          csr, ptr_pad, pairs);

    agg_l2_k<<<NB_AGG, 256, 0, stream>>>(pairs, m1c1, x2, ptr_pad, csr,
                                         w2, b2, bn2g, bn2b, bn2rm, bn2rv);
    agg_gemm_k<<<NB_AGG, 256, 0, stream>>>(x2, x3, ptr_pad, csr, pairs,
                                           w3, b3, bn3g, bn3b, bn3rm, bn3rv);

    pool_mlp_k<<<N_GRAPH, 256, 0, stream>>>(x3, batch, wl1, bl1, wl2, bl2,
                                            bnlg, bnlb, bnlrm, bnlrv, out);
}